// Round 6
// baseline (176.489 us; speedup 1.0000x reference)
//
#include <hip/hip_runtime.h>
#include <hip/hip_bf16.h>

#define TEMP_INV 14.285714285714286f  // 1/0.07
#define FSCALE 16.0f                  // fp8 pre-scale per operand
#define T1S (TEMP_INV / 256.0f)       // acc = 256*sim -> (sim-1)/T = acc*T1S - TEMP_INV

typedef __attribute__((ext_vector_type(4))) float f32x4;
typedef __attribute__((ext_vector_type(4))) int i32x4;
typedef __attribute__((ext_vector_type(8))) int i32x8;

// ---- fq FRAGMENT-MAJOR layout ----
// fq is organized in 2KB tiles: tile(rg, kb) with rg = row/16, kb = kbyte/128.
// Within a tile, byte (row r16, k-offset o in [0,128)) lives at:
//   slot = ((o>>4)&1)*64 + (o>>5)*16 + r16 ;  addr = slot*16 + (o&15)
// An MFMA fragment (lane = quad*16+l15 wants row l15, k = quad*32..+32)
// reads lo16B at tile+lane*16, hi16B at tile+1024+lane*16 -> two perfectly
// lane-consecutive 1KB global loads per fragment.

// ---- row L2-normalize -> fp8 e4m3 (x16) into fragment-major layout ----
__global__ __launch_bounds__(256) void norm_k(const float* __restrict__ feat,
                                              uchar* __restrict__ fq,
                                              const int* __restrict__ labels,
                                              const int* __restrict__ kptr,
                                              int* __restrict__ glab,
                                              float* __restrict__ gacc,
                                              int* __restrict__ dcnt,
                                              int N, int D) {
  const int row = (blockIdx.x * 256 + threadIdx.x) >> 6;
  const int lane = threadIdx.x & 63;
  if (row < N) {
    const float4* fr = (const float4*)(feat + (size_t)row * D);
    float4 v0 = fr[lane * 2];
    float4 v1 = fr[lane * 2 + 1];
    float ss = v0.x * v0.x + v0.y * v0.y + v0.z * v0.z + v0.w * v0.w +
               v1.x * v1.x + v1.y * v1.y + v1.z * v1.z + v1.w * v1.w;
    #pragma unroll
    for (int off = 32; off; off >>= 1) ss += __shfl_xor(ss, off, 64);
    const float inv = FSCALE / fmaxf(sqrtf(ss), 1e-12f);
    int w0 = 0, w1 = 0;
    w0 = __builtin_amdgcn_cvt_pk_fp8_f32(v0.x * inv, v0.y * inv, w0, false);
    w0 = __builtin_amdgcn_cvt_pk_fp8_f32(v0.z * inv, v0.w * inv, w0, true);
    w1 = __builtin_amdgcn_cvt_pk_fp8_f32(v1.x * inv, v1.y * inv, w1, false);
    w1 = __builtin_amdgcn_cvt_pk_fp8_f32(v1.z * inv, v1.w * inv, w1, true);
    uint2 o; o.x = (uint)w0; o.y = (uint)w1;
    // lane covers kbytes [lane*8, lane*8+8) of this row
    const int tkb  = lane >> 4;          // k-block tile
    const int quad = (lane >> 2) & 3;    // (kbyte%128)>>5
    const int half = (lane >> 1) & 1;    // (kbyte%32)>>4
    const int slot = half * 64 + quad * 16 + (row & 15);
    uchar* dstp = fq + (((size_t)(row >> 4) * (D >> 7) + tkb) << 11) +
                  slot * 16 + (lane & 1) * 8;
    *(uint2*)dstp = o;
    if (lane == 0) {
      const int k = *kptr;
      glab[row] = labels[(size_t)(row / k) * k];
    }
  }
  if (blockIdx.x == 0 && threadIdx.x < 3) {
    if (threadIdx.x < 2) gacc[threadIdx.x] = 0.f;
    else *dcnt = 0;
  }
}

// ---- fused MX-fp8 GEMM + masked-softmax-stats, upper-triangle blocks ----
// r19: PERSISTENT blocks. Grid = total/2 blocks, each grid-strides over 2
// tile indices (same XCD-swizzled decode per index). __launch_bounds__(256,4)
// pins 4 waves/SIMD resident for the whole kernel -> latency chains overlap
// via TLP instead of being exposed at ~1.3 waves/SIMD residency (r13..r18
// all hit the same 58us wall regardless of internal structure; every pipe
// <32% busy -> residency-bound, not pipe-bound).
// K-loop/epilogue = r17's proven code (barrier-free fragment-major direct-
// global, serial loads, VGPR-lean).
__global__ __launch_bounds__(256, 4) void gemm_k(const uchar* __restrict__ fq,
                                                 const int* __restrict__ glab,
                                                 float* __restrict__ part,
                                                 int N, int D) {
  __shared__ float sf[1024];
  const int t = threadIdx.x;
  const int lane = t & 63;
  const int wid = t >> 6;
  const int wrow = wid >> 1, wcol = wid & 1;
  const int quad = lane >> 4, l15 = lane & 15;

  const int nb = N / 128;
  const int total = nb * (nb + 1) / 2;
  const int ktiles = D >> 7;

  for (int g = blockIdx.x; g < total; g += gridDim.x) {
    int gidx = g;
    if ((total & 7) == 0) {
      const int per = total >> 3;
      gidx = (g & 7) * per + (g >> 3);
    }
    int idx = gidx, bi = 0;
    while (idx >= nb - bi) { idx -= nb - bi; bi++; }
    const int bj = bi + idx;
    const int i0 = bi * 128, j0 = bj * 128;
    const bool diagblk = (bi == bj);

    f32x4 acc[4][4];
    #pragma unroll
    for (int mi = 0; mi < 4; mi++)
      #pragma unroll
      for (int ni = 0; ni < 4; ni++) {
        f32x4 z = {0.f, 0.f, 0.f, 0.f};
        acc[mi][ni] = z;
      }

    const uchar* ap = fq + (((size_t)((i0 >> 4) + wrow * 4) * ktiles) << 11) + lane * 16;
    const uchar* bp = fq + (((size_t)((j0 >> 4) + wcol * 4) * ktiles) << 11) + lane * 16;

#define KSTEP(kt)                                                             \
    {                                                                         \
      i32x8 bv[4];                                                            \
      _Pragma("unroll")                                                       \
      for (int ni = 0; ni < 4; ni++) {                                        \
        const uchar* p = bp + (((ni) * ktiles + (kt)) << 11);                 \
        i32x4 lo = *(const i32x4*)p;                                          \
        i32x4 hi = *(const i32x4*)(p + 1024);                                 \
        bv[ni] = (i32x8){lo.x, lo.y, lo.z, lo.w, hi.x, hi.y, hi.z, hi.w};     \
      }                                                                       \
      _Pragma("unroll")                                                       \
      for (int mi = 0; mi < 4; mi++) {                                        \
        const uchar* p = ap + (((mi) * ktiles + (kt)) << 11);                 \
        i32x4 lo = *(const i32x4*)p;                                          \
        i32x4 hi = *(const i32x4*)(p + 1024);                                 \
        i32x8 av = (i32x8){lo.x, lo.y, lo.z, lo.w, hi.x, hi.y, hi.z, hi.w};   \
        _Pragma("unroll")                                                     \
        for (int ni = 0; ni < 4; ni++)                                        \
          acc[mi][ni] = __builtin_amdgcn_mfma_scale_f32_16x16x128_f8f6f4(     \
              av, bv[ni], acc[mi][ni], 0, 0, 0, 127, 0, 127);                 \
      }                                                                       \
    }

    if (ktiles == 4) {
      KSTEP(0) KSTEP(1) KSTEP(2) KSTEP(3)
    } else {
      for (int kt = 0; kt < ktiles; kt++) KSTEP(kt)
    }
#undef KSTEP

    const int colbase = j0 + wcol * 64 + l15;
    int clab[4];
    #pragma unroll
    for (int ni = 0; ni < 4; ni++) clab[ni] = glab[colbase + ni * 16];

    float colE[4] = {0.f, 0.f, 0.f, 0.f};
    float colP[4] = {0.f, 0.f, 0.f, 0.f};

    #pragma unroll
    for (int mi = 0; mi < 4; mi++) {
      const int lrw = wrow * 64 + mi * 16 + quad * 4;
      #pragma unroll
      for (int r = 0; r < 4; r++) {
        const int row = i0 + lrw + r;
        const int rlab = glab[row];
        float Ssum = 0.f, Psum = 0.f;
        #pragma unroll
        for (int ni = 0; ni < 4; ni++) {
          const int col = colbase + ni * 16;
          const float val = acc[mi][ni][r];
          const float lg = fmaf(val, T1S, -TEMP_INV);
          const bool diag = diagblk && (row == col);
          const float e = diag ? 0.f : __expf(lg);
          const float pm = (!diag && rlab == clab[ni]) ? lg : 0.f;
          Ssum += e; Psum += pm;
          colE[ni] += e; colP[ni] += pm;
        }
        #pragma unroll
        for (int off = 8; off; off >>= 1) {
          Ssum += __shfl_xor(Ssum, off, 64);
          Psum += __shfl_xor(Psum, off, 64);
        }
        if (l15 == 0) {
          sf[wcol * 128 + lrw + r]       = Ssum;
          sf[256 + wcol * 128 + lrw + r] = Psum;
        }
      }
    }
    if (!diagblk) {
      #pragma unroll
      for (int ni = 0; ni < 4; ni++) {
        float e = colE[ni];
        float p = colP[ni];
        e += __shfl_xor(e, 16, 64);
        e += __shfl_xor(e, 32, 64);
        p += __shfl_xor(p, 16, 64);
        p += __shfl_xor(p, 32, 64);
        const int lcol = wcol * 64 + ni * 16 + l15;
        if (quad == 0) {
          sf[512 + wrow * 128 + lcol] = e;
          sf[768 + wrow * 128 + lcol] = p;
        }
      }
    }
    __syncthreads();
    float* dst = part + (size_t)gidx * 512;
    if (t < 128) {
      dst[t]       = sf[t] + sf[128 + t];
      dst[128 + t] = sf[256 + t] + sf[384 + t];
    } else if (!diagblk) {
      const int u = t - 128;
      dst[256 + u] = sf[512 + u] + sf[640 + u];
      dst[384 + u] = sf[768 + u] + sf[896 + u];
    }
    __syncthreads();  // protect sf before next iteration's writes
  }
}

// ---- gather partials (8-way sliced) + in-block histogram -> loss ----
__global__ __launch_bounds__(1024) void reduce_loss_k(const float* __restrict__ part,
                                                      const int* __restrict__ glab,
                                                      const int* __restrict__ labels,
                                                      const int* __restrict__ kptr,
                                                      float* __restrict__ gacc,
                                                      int* __restrict__ dcnt,
                                                      float* __restrict__ out, int N) {
  const int nb = N / 128;
  const int b = blockIdx.x;
  const int tt = threadIdx.x;
  const int t = tt & 127;    // row within strip
  const int sl = tt >> 7;    // slice 0..7
  const int k = *kptr;
  const int B = N / k;

  __shared__ int h[64];
  if (tt < 64) h[tt] = 0;
  __syncthreads();
  for (int g = tt; g < B; g += 1024) {
    int lb = labels[(size_t)g * k];
    if (lb >= 0 && lb < 64) atomicAdd(&h[lb], 1);
  }

  float S = 0.f, P = 0.f;
  const int base = b * nb - b * (b - 1) / 2;
  for (int bj = b + sl; bj < nb; bj += 8) {   // row-side partials
    const float* p = part + (size_t)(base + bj - b) * 512;
    S += p[t];
    P += p[128 + t];
  }
  for (int bi = sl; bi < b; bi += 8) {        // col-side partials (symmetry)
    const int idx = bi * nb - bi * (bi - 1) / 2 + (b - bi);
    const float* p = part + (size_t)idx * 512;
    S += p[256 + t];
    P += p[384 + t];
  }
  __shared__ float sS[8][128], sP[8][128];
  sS[sl][t] = S; sP[sl][t] = P;
  __syncthreads();
  float l = 0.f, v = 0.f;
  if (sl == 0) {
    S = 0.f; P = 0.f;
    #pragma unroll
    for (int s = 0; s < 8; s++) { S += sS[s][t]; P += sP[s][t]; }
    const int np = h[glab[b * 128 + t]] * k - 1;
    if (np > 0) {
      l = -(P - (float)np * logf(S + 1e-8f)) / (float)np;
      v = 1.f;
    }
  }
  #pragma unroll
  for (int off = 32; off; off >>= 1) {
    l += __shfl_xor(l, off, 64);
    v += __shfl_xor(v, off, 64);
  }
  __shared__ float sl16[16], sv16[16];
  if ((tt & 63) == 0) { sl16[tt >> 6] = l; sv16[tt >> 6] = v; }
  __syncthreads();
  if (tt == 0) {
    float L = 0.f, V = 0.f;
    #pragma unroll
    for (int i = 0; i < 16; i++) { L += sl16[i]; V += sv16[i]; }
    atomicAdd(&gacc[0], L);
    atomicAdd(&gacc[1], V);
    __threadfence();
    const int prev = atomicAdd(dcnt, 1);
    if (prev == (int)gridDim.x - 1) {
      const float Lf = atomicAdd(&gacc[0], 0.f);
      const float Vf = atomicAdd(&gacc[1], 0.f);
      out[0] = Lf / fmaxf(Vf, 1.f);
    }
  }
}

extern "C" void kernel_launch(void* const* d_in, const int* in_sizes, int n_in,
                              void* d_out, int out_size, void* d_ws, size_t ws_size,
                              hipStream_t stream) {
  const float* feat = (const float*)d_in[0];
  const int* labels = (const int*)d_in[1];
  const int* kptr   = (const int*)d_in[2];
  const int N = in_sizes[1];
  const int D = in_sizes[0] / N;  // 512

  const int nb = N / 128;
  const int total = nb * (nb + 1) / 2;

  char* ws = (char*)d_ws;
  uchar* fq = (uchar*)ws;
  size_t off = (size_t)N * D;  // fp8: 1 byte/elem
  float* part = (float*)(ws + off); off += (size_t)total * 512 * sizeof(float);
  int* glab   = (int*)(ws + off);   off += (size_t)N * sizeof(int);
  float* gacc = (float*)(ws + off); off += 2 * sizeof(float);
  int* dcnt   = (int*)(ws + off);   off += sizeof(int);

  // persistent grid: ~2 tiles per block, 4 blocks/CU resident
  int pgrid = (total + 1) / 2;
  if (pgrid > total) pgrid = total;

  norm_k<<<(N + 3) / 4, 256, 0, stream>>>(feat, fq, labels, kptr, glab,
                                          gacc, dcnt, N, D);
  gemm_k<<<pgrid, 256, 0, stream>>>(fq, glab, part, N, D);
  reduce_loss_k<<<nb, 1024, 0, stream>>>(part, glab, labels, kptr, gacc, dcnt,
                                         (float*)d_out, N);
}

// Round 7
// 133.595 us; speedup vs baseline: 1.3211x; 1.3211x over previous
//
#include <hip/hip_runtime.h>
#include <hip/hip_bf16.h>

#define TEMP_INV 14.285714285714286f  // 1/0.07
#define FSCALE 16.0f                  // fp8 pre-scale per operand
#define T1S (TEMP_INV / 256.0f)       // acc = 256*sim -> (sim-1)/T = acc*T1S - TEMP_INV

typedef __attribute__((ext_vector_type(4))) float f32x4;
typedef __attribute__((ext_vector_type(4))) int i32x4;
typedef __attribute__((ext_vector_type(8))) int i32x8;

// ---- fq FRAGMENT-MAJOR layout ----
// fq is organized in 2KB tiles: tile(rg, kb) with rg = row/16, kb = kbyte/128.
// Within a tile, byte (row r16, k-offset o in [0,128)) lives at:
//   slot = ((o>>4)&1)*64 + (o>>5)*16 + r16 ;  addr = slot*16 + (o&15)
// An MFMA fragment (lane = quad*16+l15 wants row l15, k = quad*32..+32)
// reads lo16B at tile+lane*16, hi16B at tile+1024+lane*16 -> two perfectly
// lane-consecutive 1KB global loads per fragment.

// ---- row L2-normalize -> fp8 e4m3 (x16) into fragment-major layout ----
__global__ __launch_bounds__(256) void norm_k(const float* __restrict__ feat,
                                              uchar* __restrict__ fq,
                                              const int* __restrict__ labels,
                                              const int* __restrict__ kptr,
                                              int* __restrict__ glab,
                                              float* __restrict__ gacc,
                                              int* __restrict__ dcnt,
                                              int N, int D) {
  const int row = (blockIdx.x * 256 + threadIdx.x) >> 6;
  const int lane = threadIdx.x & 63;
  if (row < N) {
    const float4* fr = (const float4*)(feat + (size_t)row * D);
    float4 v0 = fr[lane * 2];
    float4 v1 = fr[lane * 2 + 1];
    float ss = v0.x * v0.x + v0.y * v0.y + v0.z * v0.z + v0.w * v0.w +
               v1.x * v1.x + v1.y * v1.y + v1.z * v1.z + v1.w * v1.w;
    #pragma unroll
    for (int off = 32; off; off >>= 1) ss += __shfl_xor(ss, off, 64);
    const float inv = FSCALE / fmaxf(sqrtf(ss), 1e-12f);
    int w0 = 0, w1 = 0;
    w0 = __builtin_amdgcn_cvt_pk_fp8_f32(v0.x * inv, v0.y * inv, w0, false);
    w0 = __builtin_amdgcn_cvt_pk_fp8_f32(v0.z * inv, v0.w * inv, w0, true);
    w1 = __builtin_amdgcn_cvt_pk_fp8_f32(v1.x * inv, v1.y * inv, w1, false);
    w1 = __builtin_amdgcn_cvt_pk_fp8_f32(v1.z * inv, v1.w * inv, w1, true);
    uint2 o; o.x = (uint)w0; o.y = (uint)w1;
    // lane covers kbytes [lane*8, lane*8+8) of this row
    const int tkb  = lane >> 4;          // k-block tile
    const int quad = (lane >> 2) & 3;    // (kbyte%128)>>5
    const int half = (lane >> 1) & 1;    // (kbyte%32)>>4
    const int slot = half * 64 + quad * 16 + (row & 15);
    uchar* dstp = fq + (((size_t)(row >> 4) * (D >> 7) + tkb) << 11) +
                  slot * 16 + (lane & 1) * 8;
    *(uint2*)dstp = o;
    if (lane == 0) {
      const int k = *kptr;
      glab[row] = labels[(size_t)(row / k) * k];
    }
  }
  if (blockIdx.x == 0 && threadIdx.x < 3) {
    if (threadIdx.x < 2) gacc[threadIdx.x] = 0.f;
    else *dcnt = 0;
  }
}

// ---- fused MX-fp8 GEMM + masked-softmax-stats, 64x64 tiles, 1 WAVE/BLOCK --
// r20: decisive residency test. Each 64-thread block = one wave owning a
// full 64x64 tile (r17's proven per-wave workload: 64 coalesced 1KB loads +
// 64 mfma_scale + wave-local epilogue). ZERO LDS, ZERO barriers, ~100 VGPR
// -> HW can pack ~5 waves/SIMD (2.5x the 4-wave-block residency), and
// 1-wave workgroups backfill wave slots freely. Triangular decode is
// closed-form (no 64-iter scalar loop). part = 256 floats/tile:
// [0:64) S_row  [64:128) P_row  [128:192) E_col  [192:256) P_col.
__global__ __launch_bounds__(64) void gemm_k(const uchar* __restrict__ fq,
                                             const int* __restrict__ glab,
                                             float* __restrict__ part,
                                             int N, int D) {
  const int lane = threadIdx.x;
  const int quad = lane >> 4, l15 = lane & 15;

  const int nbs = N / 64;
  const int total = nbs * (nbs + 1) / 2;
  int gidx = blockIdx.x;
  if ((total & 7) == 0) {
    const int per = total >> 3;
    gidx = (blockIdx.x & 7) * per + (blockIdx.x >> 3);
  }
  // closed-form triangular decode with fixup
  const float nf = (float)nbs + 0.5f;
  int bi = (int)(nf - sqrtf(fmaxf(nf * nf - 2.0f * (float)gidx, 0.f)));
  if (bi < 0) bi = 0;
  if (bi > nbs - 1) bi = nbs - 1;
  while (bi > 0 && bi * nbs - bi * (bi - 1) / 2 > gidx) bi--;
  while ((bi + 1) * nbs - (bi + 1) * bi / 2 <= gidx) bi++;
  const int bj = bi + (gidx - (bi * nbs - bi * (bi - 1) / 2));
  const int i0 = bi * 64, j0 = bj * 64;
  const bool diagblk = (bi == bj);

  f32x4 acc[4][4];
  #pragma unroll
  for (int mi = 0; mi < 4; mi++)
    #pragma unroll
    for (int ni = 0; ni < 4; ni++) {
      f32x4 z = {0.f, 0.f, 0.f, 0.f};
      acc[mi][ni] = z;
    }

  const int ktiles = D >> 7;
  // A row-group = i0/16 + mi, B row-group = j0/16 + ni
  const uchar* ap = fq + (((size_t)(i0 >> 4) * ktiles) << 11) + lane * 16;
  const uchar* bp = fq + (((size_t)(j0 >> 4) * ktiles) << 11) + lane * 16;

#define KSTEP(kt)                                                             \
  {                                                                           \
    i32x8 bv[4];                                                              \
    _Pragma("unroll")                                                         \
    for (int ni = 0; ni < 4; ni++) {                                          \
      const uchar* p = bp + (((ni) * ktiles + (kt)) << 11);                   \
      i32x4 lo = *(const i32x4*)p;                                            \
      i32x4 hi = *(const i32x4*)(p + 1024);                                   \
      bv[ni] = (i32x8){lo.x, lo.y, lo.z, lo.w, hi.x, hi.y, hi.z, hi.w};       \
    }                                                                         \
    _Pragma("unroll")                                                         \
    for (int mi = 0; mi < 4; mi++) {                                          \
      const uchar* p = ap + (((mi) * ktiles + (kt)) << 11);                   \
      i32x4 lo = *(const i32x4*)p;                                            \
      i32x4 hi = *(const i32x4*)(p + 1024);                                   \
      i32x8 av = (i32x8){lo.x, lo.y, lo.z, lo.w, hi.x, hi.y, hi.z, hi.w};     \
      _Pragma("unroll")                                                       \
      for (int ni = 0; ni < 4; ni++)                                          \
        acc[mi][ni] = __builtin_amdgcn_mfma_scale_f32_16x16x128_f8f6f4(       \
            av, bv[ni], acc[mi][ni], 0, 0, 0, 127, 0, 127);                   \
    }                                                                         \
  }

  if (ktiles == 4) {
    KSTEP(0) KSTEP(1) KSTEP(2) KSTEP(3)
  } else {
    for (int kt = 0; kt < ktiles; kt++) KSTEP(kt)
  }
#undef KSTEP

  int clab[4];
  #pragma unroll
  for (int ni = 0; ni < 4; ni++) clab[ni] = glab[j0 + ni * 16 + l15];

  float colE[4] = {0.f, 0.f, 0.f, 0.f};
  float colP[4] = {0.f, 0.f, 0.f, 0.f};
  float* dst = part + (size_t)gidx * 256;

  #pragma unroll
  for (int mi = 0; mi < 4; mi++) {
    const int lrw = mi * 16 + quad * 4;
    #pragma unroll
    for (int r = 0; r < 4; r++) {
      const int row = i0 + lrw + r;
      const int rlab = glab[row];
      float Ssum = 0.f, Psum = 0.f;
      #pragma unroll
      for (int ni = 0; ni < 4; ni++) {
        const int col = j0 + ni * 16 + l15;
        const float val = acc[mi][ni][r];
        const float lg = fmaf(val, T1S, -TEMP_INV);
        const bool diag = diagblk && (row == col);
        const float e = diag ? 0.f : __expf(lg);
        const float pm = (!diag && rlab == clab[ni]) ? lg : 0.f;
        Ssum += e; Psum += pm;
        colE[ni] += e; colP[ni] += pm;
      }
      #pragma unroll
      for (int off = 8; off; off >>= 1) {
        Ssum += __shfl_xor(Ssum, off, 64);
        Psum += __shfl_xor(Psum, off, 64);
      }
      if (l15 == 0) {
        dst[lrw + r]      = Ssum;
        dst[64 + lrw + r] = Psum;
      }
    }
  }
  if (!diagblk) {
    #pragma unroll
    for (int ni = 0; ni < 4; ni++) {
      float e = colE[ni];
      float p = colP[ni];
      e += __shfl_xor(e, 16, 64);
      e += __shfl_xor(e, 32, 64);
      p += __shfl_xor(p, 16, 64);
      p += __shfl_xor(p, 32, 64);
      if (quad == 0) {
        dst[128 + ni * 16 + l15] = e;
        dst[192 + ni * 16 + l15] = p;
      }
    }
  }
}

// ---- gather partials (16-way sliced over 64-row strips) + histogram ----
__global__ __launch_bounds__(1024) void reduce_loss_k(const float* __restrict__ part,
                                                      const int* __restrict__ glab,
                                                      const int* __restrict__ labels,
                                                      const int* __restrict__ kptr,
                                                      float* __restrict__ gacc,
                                                      int* __restrict__ dcnt,
                                                      float* __restrict__ out, int N) {
  const int nbs = N / 64;
  const int b = blockIdx.x;
  const int tt = threadIdx.x;
  const int t = tt & 63;     // row within strip
  const int sl = tt >> 6;    // slice 0..15
  const int k = *kptr;
  const int B = N / k;

  __shared__ int h[64];
  if (tt < 64) h[tt] = 0;
  __syncthreads();
  for (int g = tt; g < B; g += 1024) {
    int lb = labels[(size_t)g * k];
    if (lb >= 0 && lb < 64) atomicAdd(&h[lb], 1);
  }

  float S = 0.f, P = 0.f;
  const int base = b * nbs - b * (b - 1) / 2;
  for (int bj = b + sl; bj < nbs; bj += 16) {  // row-side partials
    const float* p = part + (size_t)(base + bj - b) * 256;
    S += p[t];
    P += p[64 + t];
  }
  for (int bi = sl; bi < b; bi += 16) {        // col-side partials (symmetry)
    const int idx = bi * nbs - bi * (bi - 1) / 2 + (b - bi);
    const float* p = part + (size_t)idx * 256;
    S += p[128 + t];
    P += p[192 + t];
  }
  __shared__ float sS[16][64], sP[16][64];
  sS[sl][t] = S; sP[sl][t] = P;
  __syncthreads();
  float l = 0.f, v = 0.f;
  if (sl == 0) {
    S = 0.f; P = 0.f;
    #pragma unroll
    for (int s = 0; s < 16; s++) { S += sS[s][t]; P += sP[s][t]; }
    const int np = h[glab[b * 64 + t]] * k - 1;
    if (np > 0) {
      l = -(P - (float)np * logf(S + 1e-8f)) / (float)np;
      v = 1.f;
    }
  }
  #pragma unroll
  for (int off = 32; off; off >>= 1) {
    l += __shfl_xor(l, off, 64);
    v += __shfl_xor(v, off, 64);
  }
  __shared__ float sl16[16], sv16[16];
  if ((tt & 63) == 0) { sl16[tt >> 6] = l; sv16[tt >> 6] = v; }
  __syncthreads();
  if (tt == 0) {
    float L = 0.f, V = 0.f;
    #pragma unroll
    for (int i = 0; i < 16; i++) { L += sl16[i]; V += sv16[i]; }
    atomicAdd(&gacc[0], L);
    atomicAdd(&gacc[1], V);
    __threadfence();
    const int prev = atomicAdd(dcnt, 1);
    if (prev == (int)gridDim.x - 1) {
      const float Lf = atomicAdd(&gacc[0], 0.f);
      const float Vf = atomicAdd(&gacc[1], 0.f);
      out[0] = Lf / fmaxf(Vf, 1.f);
    }
  }
}

extern "C" void kernel_launch(void* const* d_in, const int* in_sizes, int n_in,
                              void* d_out, int out_size, void* d_ws, size_t ws_size,
                              hipStream_t stream) {
  const float* feat = (const float*)d_in[0];
  const int* labels = (const int*)d_in[1];
  const int* kptr   = (const int*)d_in[2];
  const int N = in_sizes[1];
  const int D = in_sizes[0] / N;  // 512

  const int nbs = N / 64;
  const int total = nbs * (nbs + 1) / 2;  // 8256 at N=8192

  char* ws = (char*)d_ws;
  uchar* fq = (uchar*)ws;
  size_t off = (size_t)N * D;  // fp8: 1 byte/elem
  float* part = (float*)(ws + off); off += (size_t)total * 256 * sizeof(float);
  int* glab   = (int*)(ws + off);   off += (size_t)N * sizeof(int);
  float* gacc = (float*)(ws + off); off += 2 * sizeof(float);
  int* dcnt   = (int*)(ws + off);   off += sizeof(int);

  norm_k<<<(N + 3) / 4, 256, 0, stream>>>(feat, fq, labels, kptr, glab,
                                          gacc, dcnt, N, D);
  gemm_k<<<total, 64, 0, stream>>>(fq, glab, part, N, D);
  reduce_loss_k<<<nbs, 1024, 0, stream>>>(part, glab, labels, kptr, gacc, dcnt,
                                          (float*)d_out, N);
}

// Round 8
// 125.713 us; speedup vs baseline: 1.4039x; 1.0627x over previous
//
#include <hip/hip_runtime.h>
#include <hip/hip_bf16.h>

#define TEMP_INV 14.285714285714286f  // 1/0.07
#define FSCALE 16.0f                  // fp8 pre-scale per operand
#define T1S (TEMP_INV / 256.0f)       // acc = 256*sim -> (sim-1)/T = acc*T1S - TEMP_INV

typedef __attribute__((ext_vector_type(4))) float f32x4;
typedef __attribute__((ext_vector_type(4))) int i32x4;
typedef __attribute__((ext_vector_type(8))) int i32x8;

// ---- fq FRAGMENT-MAJOR layout ----
// fq is organized in 2KB tiles: tile(rg, kb) with rg = row/16, kb = kbyte/128.
// Within a tile, byte (row r16, k-offset o in [0,128)) lives at:
//   slot = ((o>>4)&1)*64 + (o>>5)*16 + r16 ;  addr = slot*16 + (o&15)
// An MFMA fragment (lane = quad*16+l15 wants row l15, k = quad*32..+32)
// reads lo16B at tile+lane*16, hi16B at tile+1024+lane*16 -> two perfectly
// lane-consecutive 1KB global loads per fragment.

// ---- row L2-normalize -> fp8 e4m3 (x16) into fragment-major layout ----
__global__ __launch_bounds__(256) void norm_k(const float* __restrict__ feat,
                                              uchar* __restrict__ fq,
                                              const int* __restrict__ labels,
                                              const int* __restrict__ kptr,
                                              int* __restrict__ glab,
                                              float* __restrict__ gacc,
                                              int* __restrict__ dcnt,
                                              int N, int D) {
  const int row = (blockIdx.x * 256 + threadIdx.x) >> 6;
  const int lane = threadIdx.x & 63;
  if (row < N) {
    const float4* fr = (const float4*)(feat + (size_t)row * D);
    float4 v0 = fr[lane * 2];
    float4 v1 = fr[lane * 2 + 1];
    float ss = v0.x * v0.x + v0.y * v0.y + v0.z * v0.z + v0.w * v0.w +
               v1.x * v1.x + v1.y * v1.y + v1.z * v1.z + v1.w * v1.w;
    #pragma unroll
    for (int off = 32; off; off >>= 1) ss += __shfl_xor(ss, off, 64);
    const float inv = FSCALE / fmaxf(sqrtf(ss), 1e-12f);
    int w0 = 0, w1 = 0;
    w0 = __builtin_amdgcn_cvt_pk_fp8_f32(v0.x * inv, v0.y * inv, w0, false);
    w0 = __builtin_amdgcn_cvt_pk_fp8_f32(v0.z * inv, v0.w * inv, w0, true);
    w1 = __builtin_amdgcn_cvt_pk_fp8_f32(v1.x * inv, v1.y * inv, w1, false);
    w1 = __builtin_amdgcn_cvt_pk_fp8_f32(v1.z * inv, v1.w * inv, w1, true);
    uint2 o; o.x = (uint)w0; o.y = (uint)w1;
    // lane covers kbytes [lane*8, lane*8+8) of this row
    const int tkb  = lane >> 4;          // k-block tile
    const int quad = (lane >> 2) & 3;    // (kbyte%128)>>5
    const int half = (lane >> 1) & 1;    // (kbyte%32)>>4
    const int slot = half * 64 + quad * 16 + (row & 15);
    uchar* dstp = fq + (((size_t)(row >> 4) * (D >> 7) + tkb) << 11) +
                  slot * 16 + (lane & 1) * 8;
    *(uint2*)dstp = o;
    if (lane == 0) {
      const int k = *kptr;
      glab[row] = labels[(size_t)(row / k) * k];
    }
  }
  if (blockIdx.x == 0 && threadIdx.x < 3) {
    if (threadIdx.x < 2) gacc[threadIdx.x] = 0.f;
    else *dcnt = 0;
  }
}

// ---- flash-style fused GEMM + online masked-softmax stats ----
// r21: each WAVE owns a 32-row strip and loops a 1024-col slice (16 j-steps
// of 64 cols, FULL matrix -> no col-side partials, no triangle decode).
// A-fragments (strip x D) register-cached ONCE (64 VGPR), reused 16x.
// Per j-step: 16 coalesced B-loads + 32 MFMA + pure-VALU online S/P accum
// (no shuffles, no stores). Shuffle-reduce + part store ONCE per strip ->
// cross-lane ops drop 16x vs per-tile epilogue; waves are long-lived so
// fill latency + epilogue drain amortize over 16 tiles.
// slice = blockIdx&7 pins each B-slice to one XCD's L2.
// 2 waves/block (no shared state, no barriers), grid = (N/64)*8 = 1024.
__global__ __launch_bounds__(128) void gemm_k(const uchar* __restrict__ fq,
                                              const int* __restrict__ glab,
                                              float* __restrict__ partS,
                                              float* __restrict__ partP,
                                              int N, int D) {
  const int lane = threadIdx.x & 63;
  const int wid  = threadIdx.x >> 6;
  const int quad = lane >> 4, l15 = lane & 15;
  const int ktiles = D >> 7;              // 4 at D=512
  const int strip = (blockIdx.x >> 3) * 2 + wid;   // 0..N/32-1
  const int slice = blockIdx.x & 7;                // XCD-pinned col slice
  const int r0 = strip * 32;
  const int cps = N >> 3;                 // cols per slice (1024)
  const int jsteps = cps >> 6;            // 16
  const int j0base = slice * cps;

  // per-lane labels for this strip's rows (row = r0 + mi*16 + quad*4 + r)
  int rlab[2][4];
  #pragma unroll
  for (int mi = 0; mi < 2; mi++)
    #pragma unroll
    for (int r = 0; r < 4; r++)
      rlab[mi][r] = glab[r0 + mi * 16 + quad * 4 + r];

  float Srun[2][4] = {{0.f, 0.f, 0.f, 0.f}, {0.f, 0.f, 0.f, 0.f}};
  float Prun[2][4] = {{0.f, 0.f, 0.f, 0.f}, {0.f, 0.f, 0.f, 0.f}};

#define LOADF(dst, grp, kt)                                                   \
  {                                                                           \
    const uchar* p_ = fq + (((size_t)((grp) * ktiles + (kt))) << 11) + lane * 16; \
    i32x4 lo_ = *(const i32x4*)p_;                                            \
    i32x4 hi_ = *(const i32x4*)(p_ + 1024);                                   \
    dst = (i32x8){lo_.x, lo_.y, lo_.z, lo_.w, hi_.x, hi_.y, hi_.z, hi_.w};    \
  }

  if (ktiles == 4) {
    // A-fragments register-cached once for the whole strip
    i32x8 af[2][4];
    #pragma unroll
    for (int mi = 0; mi < 2; mi++)
      #pragma unroll
      for (int kt = 0; kt < 4; kt++)
        LOADF(af[mi][kt], (r0 >> 4) + mi, kt)

    for (int js = 0; js < jsteps; js++) {
      const int j0 = j0base + js * 64;
      f32x4 acc[2][4];
      #pragma unroll
      for (int mi = 0; mi < 2; mi++)
        #pragma unroll
        for (int ni = 0; ni < 4; ni++) {
          f32x4 z = {0.f, 0.f, 0.f, 0.f};
          acc[mi][ni] = z;
        }
      #pragma unroll
      for (int kt = 0; kt < 4; kt++) {
        i32x8 bv[4];
        #pragma unroll
        for (int ni = 0; ni < 4; ni++)
          LOADF(bv[ni], (j0 >> 4) + ni, kt)
        #pragma unroll
        for (int mi = 0; mi < 2; mi++)
          #pragma unroll
          for (int ni = 0; ni < 4; ni++)
            acc[mi][ni] = __builtin_amdgcn_mfma_scale_f32_16x16x128_f8f6f4(
                af[mi][kt], bv[ni], acc[mi][ni], 0, 0, 0, 127, 0, 127);
      }
      int clab[4];
      #pragma unroll
      for (int ni = 0; ni < 4; ni++) clab[ni] = glab[j0 + ni * 16 + l15];
      #pragma unroll
      for (int mi = 0; mi < 2; mi++)
        #pragma unroll
        for (int r = 0; r < 4; r++) {
          const int row = r0 + mi * 16 + quad * 4 + r;
          const int rl = rlab[mi][r];
          float s = 0.f, pp = 0.f;
          #pragma unroll
          for (int ni = 0; ni < 4; ni++) {
            const int col = j0 + ni * 16 + l15;
            const float lg = fmaf(acc[mi][ni][r], T1S, -TEMP_INV);
            const bool diag = (col == row);
            s += diag ? 0.f : __expf(lg);
            pp += (!diag && rl == clab[ni]) ? lg : 0.f;
          }
          Srun[mi][r] += s;
          Prun[mi][r] += pp;
        }
    }
  } else {
    // generic fallback: stream A per k-tile (D != 512)
    for (int js = 0; js < jsteps; js++) {
      const int j0 = j0base + js * 64;
      f32x4 acc[2][4];
      #pragma unroll
      for (int mi = 0; mi < 2; mi++)
        #pragma unroll
        for (int ni = 0; ni < 4; ni++) {
          f32x4 z = {0.f, 0.f, 0.f, 0.f};
          acc[mi][ni] = z;
        }
      for (int kt = 0; kt < ktiles; kt++) {
        i32x8 as[2], bv[4];
        #pragma unroll
        for (int mi = 0; mi < 2; mi++) LOADF(as[mi], (r0 >> 4) + mi, kt)
        #pragma unroll
        for (int ni = 0; ni < 4; ni++) LOADF(bv[ni], (j0 >> 4) + ni, kt)
        #pragma unroll
        for (int mi = 0; mi < 2; mi++)
          #pragma unroll
          for (int ni = 0; ni < 4; ni++)
            acc[mi][ni] = __builtin_amdgcn_mfma_scale_f32_16x16x128_f8f6f4(
                as[mi], bv[ni], acc[mi][ni], 0, 0, 0, 127, 0, 127);
      }
      int clab[4];
      #pragma unroll
      for (int ni = 0; ni < 4; ni++) clab[ni] = glab[j0 + ni * 16 + l15];
      #pragma unroll
      for (int mi = 0; mi < 2; mi++)
        #pragma unroll
        for (int r = 0; r < 4; r++) {
          const int row = r0 + mi * 16 + quad * 4 + r;
          const int rl = rlab[mi][r];
          float s = 0.f, pp = 0.f;
          #pragma unroll
          for (int ni = 0; ni < 4; ni++) {
            const int col = j0 + ni * 16 + l15;
            const float lg = fmaf(acc[mi][ni][r], T1S, -TEMP_INV);
            const bool diag = (col == row);
            s += diag ? 0.f : __expf(lg);
            pp += (!diag && rl == clab[ni]) ? lg : 0.f;
          }
          Srun[mi][r] += s;
          Prun[mi][r] += pp;
        }
    }
  }
#undef LOADF

  // ONE shuffle-reduce per strip: sum over the 16 lanes (l15) of each quad
  #pragma unroll
  for (int mi = 0; mi < 2; mi++)
    #pragma unroll
    for (int r = 0; r < 4; r++) {
      float s = Srun[mi][r], p = Prun[mi][r];
      #pragma unroll
      for (int off = 1; off < 16; off <<= 1) {
        s += __shfl_xor(s, off, 64);
        p += __shfl_xor(p, off, 64);
      }
      if (l15 == 0) {
        const int row = r0 + mi * 16 + quad * 4 + r;
        partS[(size_t)row * 8 + slice] = s;
        partP[(size_t)row * 8 + slice] = p;
      }
    }
}

// ---- per-row slice-sum + histogram -> loss ----
__global__ __launch_bounds__(256) void reduce_loss_k(const float* __restrict__ partS,
                                                     const float* __restrict__ partP,
                                                     const int* __restrict__ glab,
                                                     const int* __restrict__ labels,
                                                     const int* __restrict__ kptr,
                                                     float* __restrict__ gacc,
                                                     int* __restrict__ dcnt,
                                                     float* __restrict__ out, int N) {
  const int tt = threadIdx.x;
  const int row = blockIdx.x * 256 + tt;
  const int k = *kptr;
  const int B = N / k;

  __shared__ int h[64];
  if (tt < 64) h[tt] = 0;
  __syncthreads();
  for (int g = tt; g < B; g += 256) {
    int lb = labels[(size_t)g * k];
    if (lb >= 0 && lb < 64) atomicAdd(&h[lb], 1);
  }
  __syncthreads();

  float l = 0.f, v = 0.f;
  if (row < N) {
    float S = 0.f, P = 0.f;
    #pragma unroll
    for (int s = 0; s < 8; s++) {
      S += partS[(size_t)row * 8 + s];
      P += partP[(size_t)row * 8 + s];
    }
    const int np = h[glab[row]] * k - 1;
    if (np > 0) {
      l = -(P - (float)np * logf(S + 1e-8f)) / (float)np;
      v = 1.f;
    }
  }
  #pragma unroll
  for (int off = 32; off; off >>= 1) {
    l += __shfl_xor(l, off, 64);
    v += __shfl_xor(v, off, 64);
  }
  __shared__ float sl4[4], sv4[4];
  if ((tt & 63) == 0) { sl4[tt >> 6] = l; sv4[tt >> 6] = v; }
  __syncthreads();
  if (tt == 0) {
    float L = 0.f, V = 0.f;
    #pragma unroll
    for (int i = 0; i < 4; i++) { L += sl4[i]; V += sv4[i]; }
    atomicAdd(&gacc[0], L);
    atomicAdd(&gacc[1], V);
    __threadfence();
    const int prev = atomicAdd(dcnt, 1);
    if (prev == (int)gridDim.x - 1) {
      const float Lf = atomicAdd(&gacc[0], 0.f);
      const float Vf = atomicAdd(&gacc[1], 0.f);
      out[0] = Lf / fmaxf(Vf, 1.f);
    }
  }
}

extern "C" void kernel_launch(void* const* d_in, const int* in_sizes, int n_in,
                              void* d_out, int out_size, void* d_ws, size_t ws_size,
                              hipStream_t stream) {
  const float* feat = (const float*)d_in[0];
  const int* labels = (const int*)d_in[1];
  const int* kptr   = (const int*)d_in[2];
  const int N = in_sizes[1];
  const int D = in_sizes[0] / N;  // 512

  char* ws = (char*)d_ws;
  uchar* fq = (uchar*)ws;
  size_t off = (size_t)N * D;  // fp8: 1 byte/elem
  float* partS = (float*)(ws + off); off += (size_t)N * 8 * sizeof(float);
  float* partP = (float*)(ws + off); off += (size_t)N * 8 * sizeof(float);
  int* glab    = (int*)(ws + off);   off += (size_t)N * sizeof(int);
  float* gacc  = (float*)(ws + off); off += 2 * sizeof(float);
  int* dcnt    = (int*)(ws + off);   off += sizeof(int);

  const int strips = N / 32;            // 256
  const int ggrid = (strips / 2) * 8;   // 1024 blocks x 128 threads

  norm_k<<<(N + 3) / 4, 256, 0, stream>>>(feat, fq, labels, kptr, glab,
                                          gacc, dcnt, N, D);
  gemm_k<<<ggrid, 128, 0, stream>>>(fq, glab, partS, partP, N, D);
  reduce_loss_k<<<(N + 255) / 256, 256, 0, stream>>>(partS, partP, glab, labels,
                                                     kptr, gacc, dcnt,
                                                     (float*)d_out, N);
}